// Round 15
// baseline (321.823 us; speedup 1.0000x reference)
//
#include <hip/hip_runtime.h>
#include <math.h>

#define BATCH 128
#define ACT 7
#define NC 100
#define CTXD 128
#define HID 512
#define QW 600               // q cols 600..699 of reference are exactly 0

typedef __attribute__((ext_vector_type(8))) __bf16 bf16x8;
typedef __attribute__((ext_vector_type(4))) float f32x4;
typedef __attribute__((ext_vector_type(4))) unsigned short u16x4;

__device__ __forceinline__ unsigned short f2bf(float f) {
    union { float f; unsigned int u; } v; v.f = f;
    unsigned int u = v.u;
    return (unsigned short)((u + 0x7fffu + ((u >> 16) & 1u)) >> 16);
}

__device__ __forceinline__ void async16(const void* g, void* l) {
    __builtin_amdgcn_global_load_lds(
        (const __attribute__((address_space(1))) unsigned int*)(uintptr_t)g,
        (__attribute__((address_space(3))) unsigned int*)(unsigned int)(uintptr_t)l,
        16, 0, 0);
}

// ---------------- prep: cvt copies + W1AT transposes + vq in ONE launch ------
// b in [0,2368): bf16 row-major copies (obs, W1C, W2, W3)
// b in [2368,3904): 32x32 transpose tiles for W1AT (6 z)
// b in [3904,3916): vq[z][k] = W3[z+1][k][:]·Wp
__global__ void prep_kernel(const float* __restrict__ obs, const float* __restrict__ W1,
                            const float* __restrict__ W2, const float* __restrict__ W3,
                            const float* __restrict__ Wp,
                            unsigned short* __restrict__ obs_bf, unsigned short* __restrict__ W1Cbf,
                            unsigned short* __restrict__ W2bf, unsigned short* __restrict__ W3bf,
                            unsigned short* __restrict__ W1AT, float* __restrict__ vq) {
    const int bidx = blockIdx.x, tid = threadIdx.x;
    if (bidx < 2368) {
        const int e = (bidx * 256 + tid) * 4;   // 2424832 elems
        const float* src; unsigned short* dst;
        if (e < 65536)        { src = obs + e; dst = obs_bf + e; }
        else if (e < 458752)  { int f = e - 65536; int i = f >> 16; int rem = f & 65535;
                                src = W1 + (size_t)(i + 1) * 328192 + 513*512 + rem; dst = W1Cbf + f; }
        else if (e < 2031616) { int f = e - 458752; src = W2 + 262144 + f; dst = W2bf + f; }
        else                  { int f = e - 2031616; src = W3 + 65536 + f; dst = W3bf + f; }
        float4 v = *(const float4*)src;
        u16x4 o; o[0] = f2bf(v.x); o[1] = f2bf(v.y); o[2] = f2bf(v.z); o[3] = f2bf(v.w);
        *(u16x4*)dst = o;
    } else if (bidx < 3904) {
        __shared__ float tile[32][33];
        const int idx = bidx - 2368;            // 0..1535
        const int z = idx >> 8, rem = idx & 255;
        const int rb = rem & 15, cb = rem >> 4;
        const float* ip = W1 + (size_t)(z + 1) * 328192;
        unsigned short* op = W1AT + (size_t)z * 262144;
        const int r0 = rb * 32, c0 = cb * 32;
        const int tx = tid & 31, ty = tid >> 5;  // 32 x 8
        #pragma unroll
        for (int j = 0; j < 32; j += 8)
            tile[ty + j][tx] = ip[(size_t)(r0 + ty + j) * 512 + c0 + tx];
        __syncthreads();
        #pragma unroll
        for (int j = 0; j < 32; j += 8)
            op[(size_t)(c0 + ty + j) * 512 + r0 + tx] = f2bf(tile[tx][ty + j]);
    } else {
        const int idx = bidx - 3904;            // 0..11
        const int z = idx >> 1, k = (idx & 1) * 256 + tid;
        const float4* row = (const float4*)(W3 + (size_t)(z + 1) * 65536 + (size_t)k * 128);
        const float4* wp4 = (const float4*)Wp;
        float s = 0.f;
        #pragma unroll 8
        for (int n = 0; n < 32; ++n) {
            float4 a = row[n], w = wp4[n];
            s += a.x*w.x + a.y*w.y + a.z*w.z + a.w*w.w;
        }
        vq[z * 512 + k] = s;
    }
}

// ---------------- Yobs[z][b][h] = obs@W1A[z+1] + b1[z+1] ---------------------
__launch_bounds__(256)
__global__ void yobs_kernel(const unsigned short* __restrict__ A,      // obs_bf [128][512]
                            const unsigned short* __restrict__ BtAll,  // W1AT [6][512][512]
                            const float* __restrict__ b1,
                            float* __restrict__ Yobs) {
    __shared__ unsigned short As[64*32];
    __shared__ unsigned short Bs[128*32];
    const int m0 = blockIdx.x * 64;
    const int n0 = blockIdx.y * 128;
    const int z  = blockIdx.z;
    const unsigned short* Bt = BtAll + (size_t)z * 262144;
    const int tid = threadIdx.x, lane = tid & 63, wave = tid >> 6;
    const int wm = wave >> 1, wn = wave & 1;
    const int srow = tid >> 2, skc = (tid & 3) * 8;
    const unsigned short* gA  = A  + (size_t)(m0 + srow) * HID + skc;
    const unsigned short* gB0 = Bt + (size_t)(n0 + srow) * HID + skc;
    const unsigned short* gB1 = gB0 + 64 * HID;
    f32x4 acc[2][4] = {};
    for (int k0 = 0; k0 < HID; k0 += 32) {
        async16(gA + k0, As + tid*8);
        async16(gB0 + k0, Bs + tid*8);
        async16(gB1 + k0, Bs + 2048 + tid*8);
        __syncthreads();
        const int q8 = (lane >> 4) * 8, l15 = lane & 15;
        bf16x8 af[2], bfr[4];
        #pragma unroll
        for (int mt = 0; mt < 2; ++mt)
            af[mt] = *(const bf16x8*)(As + (wm*32 + mt*16 + l15) * 32 + q8);
        #pragma unroll
        for (int nt = 0; nt < 4; ++nt)
            bfr[nt] = *(const bf16x8*)(Bs + (wn*64 + nt*16 + l15) * 32 + q8);
        #pragma unroll
        for (int mt = 0; mt < 2; ++mt)
            #pragma unroll
            for (int nt = 0; nt < 4; ++nt)
                acc[mt][nt] = __builtin_amdgcn_mfma_f32_16x16x32_bf16(af[mt], bfr[nt], acc[mt][nt], 0, 0, 0);
        __syncthreads();
    }
    const int colL = wn*64 + (lane & 15);
    #pragma unroll
    for (int nt = 0; nt < 4; ++nt) {
        const int col = n0 + colL + nt*16;
        const float bb = b1[(z + 1) * HID + col];
        #pragma unroll
        for (int mt = 0; mt < 2; ++mt)
            #pragma unroll
            for (int r = 0; r < 4; ++r) {
                const int row = m0 + wm*32 + mt*16 + (lane >> 4)*4 + r;
                Yobs[(size_t)z * 65536 + (size_t)row * HID + col] = acc[mt][nt][r] + bb;
            }
    }
}

// ---------------- chain: serial context chain + QOFF precompute --------------
__launch_bounds__(1024)
__global__ void chain_kernel(const float* __restrict__ Yobs, const float* __restrict__ W1,
                             const unsigned short* __restrict__ W1Cbf,
                             const unsigned short* __restrict__ W2bf,
                             const unsigned short* __restrict__ W3bf,
                             const float* __restrict__ b2, const float* __restrict__ b3,
                             const float* __restrict__ actions,
                             const float* __restrict__ Wp, const float* __restrict__ bp,
                             float* __restrict__ Y0all, float* __restrict__ QOFF) {
    const int b = blockIdx.x, t = threadIdx.x;
    __shared__ float ctx[128], h1[512], h2s[512];
    __shared__ float part[2048];
    const int pair = t & 255, kq = t >> 8;
    const int pair3 = t & 63, kq3 = t >> 6;
    if (t < 128) ctx[t] = 0.f;
    __syncthreads();
    for (int i = 1; i <= 6; ++i) {
        if (t < 128) part[t] = (ctx[t] + b3[i*128 + t]) * Wp[t];
        __syncthreads();
        if (t < 64) {
            float v = part[t] + part[t + 64];
            #pragma unroll
            for (int o = 32; o > 0; o >>= 1) v += __shfl_down(v, o, 64);
            if (t == 0) QOFF[(i-1)*128 + b] = v + bp[0];
        }
        __syncthreads();
        const float a = actions[b*ACT + i];
        float fj = floorf((a + 1.0f) * 50.0f);
        fj = fminf(fmaxf(fj, 0.0f), 99.0f);
        // ---- layer1 ctx part ----
        {
            const unsigned int* wp1 = (const unsigned int*)(W1Cbf + (size_t)(i-1)*65536) + pair;
            float acc0 = 0.f, acc1 = 0.f;
            #pragma unroll 8
            for (int k = kq*32; k < kq*32 + 32; ++k) {
                unsigned int u = wp1[k*256];
                float c = ctx[k];
                acc0 = fmaf(c, __uint_as_float(u << 16), acc0);
                acc1 = fmaf(c, __uint_as_float(u & 0xffff0000u), acc1);
            }
            *(float2*)(&part[kq*512 + 2*pair]) = make_float2(acc0, acc1);
        }
        __syncthreads();
        if (t < 256) {
            const int n2 = 2*t;
            float2 p0 = *(const float2*)(&part[n2]);
            float2 p1 = *(const float2*)(&part[512 + n2]);
            float2 p2 = *(const float2*)(&part[1024 + n2]);
            float2 p3 = *(const float2*)(&part[1536 + n2]);
            float2 yo = *(const float2*)(Yobs + (size_t)(i-1)*65536 + b*512 + n2);
            float y0a = yo.x + p0.x + p1.x + p2.x + p3.x;
            float y0b = yo.y + p0.y + p1.y + p2.y + p3.y;
            *(float2*)(Y0all + (size_t)(i-1)*65536 + b*512 + n2) = make_float2(y0a, y0b);
            const float* w1a = W1 + (size_t)i*328192 + 262144;
            float2 wv = *(const float2*)(w1a + n2);
            h1[n2]   = fmaxf(fmaf(fj, wv.x, y0a), 0.f);
            h1[n2+1] = fmaxf(fmaf(fj, wv.y, y0b), 0.f);
        }
        __syncthreads();
        // ---- layer2 ----
        {
            const unsigned int* wp2 = (const unsigned int*)(W2bf + (size_t)(i-1)*262144) + pair;
            float acc0 = 0.f, acc1 = 0.f;
            #pragma unroll 16
            for (int k = kq*128; k < kq*128 + 128; ++k) {
                unsigned int u = wp2[k*256];
                float hv = h1[k];
                acc0 = fmaf(hv, __uint_as_float(u << 16), acc0);
                acc1 = fmaf(hv, __uint_as_float(u & 0xffff0000u), acc1);
            }
            *(float2*)(&part[kq*512 + 2*pair]) = make_float2(acc0, acc1);
        }
        __syncthreads();
        if (t < 256) {
            const int n2 = 2*t;
            float2 p0 = *(const float2*)(&part[n2]);
            float2 p1 = *(const float2*)(&part[512 + n2]);
            float2 p2 = *(const float2*)(&part[1024 + n2]);
            float2 p3 = *(const float2*)(&part[1536 + n2]);
            float2 bb = *(const float2*)(b2 + i*512 + n2);
            h2s[n2]   = fmaxf(p0.x + p1.x + p2.x + p3.x + bb.x, 0.f);
            h2s[n2+1] = fmaxf(p0.y + p1.y + p2.y + p3.y + bb.y, 0.f);
        }
        __syncthreads();
        // ---- layer3 ----
        {
            const unsigned int* wp3 = (const unsigned int*)(W3bf + (size_t)(i-1)*65536) + pair3;
            float acc0 = 0.f, acc1 = 0.f;
            #pragma unroll 8
            for (int k = kq3*32; k < kq3*32 + 32; ++k) {
                unsigned int u = wp3[k*64];
                float hv = h2s[k];
                acc0 = fmaf(hv, __uint_as_float(u << 16), acc0);
                acc1 = fmaf(hv, __uint_as_float(u & 0xffff0000u), acc1);
            }
            *(float2*)(&part[kq3*128 + 2*pair3]) = make_float2(acc0, acc1);
        }
        __syncthreads();
        if (t < 128) {
            float s = 0.f;
            #pragma unroll
            for (int qg = 0; qg < 16; ++qg) s += part[qg*128 + t];
            ctx[t] = s + b3[i*128 + t] + ctx[t];
        }
        __syncthreads();
    }
}

// ---------------- sweep: piecewise-linear candidate evaluation ---------------
// Per (z,b): h1[c,k] = relu(y_k + c*w_k) is linear in c with <=1 breakpoint.
// h2[c,n] = A_c[n] + c*B_c[n]; A,B updated incrementally at events.
// q[b, z*100+c] = sum_n relu(h2+b2)*vq + QOFF. All fp32. 768 blocks x 512 thr.
__launch_bounds__(512)
__global__ void sweep_kernel(const float* __restrict__ Y0all, const float* __restrict__ W1,
                             const float* __restrict__ W2, const float* __restrict__ b2,
                             const float* __restrict__ vq, const float* __restrict__ QOFF,
                             float* __restrict__ q) {
    __shared__ int cnt[101];
    __shared__ int off[101];
    __shared__ int off2[101];
    __shared__ short ek[1040];
    __shared__ short ebk[1040];
    __shared__ float esy[1040], esw[1040];
    __shared__ float wred[800];   // [c][wave]
    const int bx = blockIdx.x;    // 0..767
    const int z = bx >> 7, b = bx & 127;
    const int t = threadIdx.x;    // 0..511
    const float y = Y0all[(size_t)z*65536 + (size_t)b*512 + t];
    const float w = W1[(size_t)(z+1)*328192 + 262144 + t];
    if (t < 101) cnt[t] = 0;
    __syncthreads();
    // event construction for k = t
    const bool act0 = (y > 0.f);
    int bk2 = -1; float s2 = 0.f;
    if (act0 && w < 0.f) {
        float r = -y / w;                        // > 0
        if (r < 100.f) {
            int c1 = (int)ceilf(r);
            if (c1 > 1 && fmaf((float)(c1 - 1), w, y) <= 0.f) c1--;
            if (fmaf((float)c1, w, y) > 0.f) c1++;
            if (c1 >= 1 && c1 <= 99) { bk2 = c1; s2 = -1.f; }
        }
    } else if (!act0 && w > 0.f) {
        float r = -y / w;                        // >= 0
        if (r < 100.f) {
            int c0 = (int)floorf(r) + 1;
            if (c0 > 1 && fmaf((float)(c0 - 1), w, y) > 0.f) c0--;
            if (fmaf((float)c0, w, y) <= 0.f) c0++;
            if (c0 >= 1 && c0 <= 99) { bk2 = c0; s2 = 1.f; }
        }
    }
    if (act0) atomicAdd(&cnt[0], 1);
    if (bk2 >= 0) atomicAdd(&cnt[bk2], 1);
    __syncthreads();
    if (t == 0) {
        int acc = 0;
        #pragma unroll 4
        for (int c = 0; c < 101; ++c) { off[c] = acc; acc += cnt[c]; }
        // off[100] == total events E0 (cnt[100] always 0)
    }
    __syncthreads();
    if (t < 101) off2[t] = off[t];
    __syncthreads();
    if (act0) {
        int p = atomicAdd(&off2[0], 1);
        ek[p] = (short)t; ebk[p] = 0; esy[p] = y; esw[p] = w;
    }
    if (bk2 >= 0) {
        int p = atomicAdd(&off2[bk2], 1);
        ek[p] = (short)t; ebk[p] = (short)bk2; esy[p] = s2 * y; esw[p] = s2 * w;
    }
    __syncthreads();
    const int E0 = off[100];
    const int Epad = (E0 + 7) & ~7;
    if (t < 8 && E0 + t < Epad) {
        ek[E0 + t] = 0; ebk[E0 + t] = 100; esy[E0 + t] = 0.f; esw[E0 + t] = 0.f;
    }
    __syncthreads();
    // sweep
    const float b2n = b2[(z+1)*512 + t];
    const float vn  = vq[z*512 + t];
    const float* W2z = W2 + (size_t)(z+1)*262144 + t;   // column t, row stride 512
    float A = 0.f, B = 0.f;
    int cnext = 0;
    const int lane = t & 63, wid = t >> 6;
    float cwv[8], cdy[8], cdw[8]; int cbk[8];
    // prologue: load chunk 0
    #pragma unroll
    for (int j = 0; j < 8; ++j) {
        if (j < Epad) {
            int k = ek[j]; cbk[j] = ebk[j]; cdy[j] = esy[j]; cdw[j] = esw[j];
            cwv[j] = W2z[(size_t)k * 512];
        } else { cbk[j] = 100; cdy[j] = 0.f; cdw[j] = 0.f; cwv[j] = 0.f; }
    }
    for (int e0 = 0; e0 < Epad; e0 += 8) {
        float nwv[8], ndy[8], ndw[8]; int nbk[8];
        const int n0e = e0 + 8;
        if (n0e < Epad) {
            #pragma unroll
            for (int j = 0; j < 8; ++j) {
                int k = ek[n0e + j]; nbk[j] = ebk[n0e + j];
                ndy[j] = esy[n0e + j]; ndw[j] = esw[n0e + j];
                nwv[j] = W2z[(size_t)k * 512];
            }
        }
        #pragma unroll
        for (int j = 0; j < 8; ++j) {
            while (cnext < cbk[j]) {
                float h = fmaf((float)cnext, B, A) + b2n;
                float en = fmaxf(h, 0.f) * vn;
                en += __shfl_xor(en, 32, 64);
                en += __shfl_xor(en, 16, 64);
                en += __shfl_xor(en, 8, 64);
                en += __shfl_xor(en, 4, 64);
                en += __shfl_xor(en, 2, 64);
                en += __shfl_xor(en, 1, 64);
                if (lane == 0) wred[cnext * 8 + wid] = en;
                ++cnext;
                if (cnext > 99) break;
            }
            A = fmaf(cdy[j], cwv[j], A);
            B = fmaf(cdw[j], cwv[j], B);
        }
        if (n0e < Epad) {
            #pragma unroll
            for (int j = 0; j < 8; ++j) {
                cwv[j] = nwv[j]; cdy[j] = ndy[j]; cdw[j] = ndw[j]; cbk[j] = nbk[j];
            }
        }
    }
    while (cnext <= 99) {
        float h = fmaf((float)cnext, B, A) + b2n;
        float en = fmaxf(h, 0.f) * vn;
        en += __shfl_xor(en, 32, 64);
        en += __shfl_xor(en, 16, 64);
        en += __shfl_xor(en, 8, 64);
        en += __shfl_xor(en, 4, 64);
        en += __shfl_xor(en, 2, 64);
        en += __shfl_xor(en, 1, 64);
        if (lane == 0) wred[cnext * 8 + wid] = en;
        ++cnext;
    }
    __syncthreads();
    if (t < 100) {
        float s = 0.f;
        #pragma unroll
        for (int p = 0; p < 8; ++p) s += wred[t * 8 + p];
        q[b * QW + z * 100 + t] = s + QOFF[z * 128 + b];
    }
}

// ---------------- lse: out[b] = logsumexp([q[b,0:600], zeros(100)]) ----------
__global__ void lse_kernel(const float* __restrict__ q, float* __restrict__ out) {
    __shared__ float red[256];
    __shared__ float qs[QW];
    const int b = blockIdx.x, t = threadIdx.x;
    for (int k = t; k < QW; k += 256) qs[k] = q[b * QW + k];
    __syncthreads();
    float m = 0.0f;   // zero tail participates in the max
    for (int k = t; k < QW; k += 256) m = fmaxf(m, qs[k]);
    red[t] = m; __syncthreads();
    for (int s = 128; s > 0; s >>= 1) { if (t < s) red[t] = fmaxf(red[t], red[t+s]); __syncthreads(); }
    m = red[0]; __syncthreads();
    float sum = 0.0f;
    for (int k = t; k < QW; k += 256) sum += expf(qs[k] - m);
    red[t] = sum; __syncthreads();
    for (int s = 128; s > 0; s >>= 1) { if (t < s) red[t] += red[t+s]; __syncthreads(); }
    if (t == 0) out[b] = logf(red[0] + 100.0f * expf(-m)) + m;
}

extern "C" void kernel_launch(void* const* d_in, const int* in_sizes, int n_in,
                              void* d_out, int out_size, void* d_ws, size_t ws_size,
                              hipStream_t stream) {
    const float* obs     = (const float*)d_in[0];
    const float* actions = (const float*)d_in[1];
    const float* W1      = (const float*)d_in[2];
    const float* b1      = (const float*)d_in[3];
    const float* W2      = (const float*)d_in[4];
    const float* b2      = (const float*)d_in[5];
    const float* W3      = (const float*)d_in[6];
    const float* b3      = (const float*)d_in[7];
    const float* Wp      = (const float*)d_in[8];
    const float* bp      = (const float*)d_in[9];
    float* out = (float*)d_out;
    float* ws  = (float*)d_ws;

    // workspace layout (float offsets)
    unsigned short* obs_bf = (unsigned short*)(ws);            // 32768 f
    unsigned short* W1AT   = (unsigned short*)(ws + 32768);    // 786432 f
    unsigned short* W1Cbf  = (unsigned short*)(ws + 819200);   // 196608 f
    unsigned short* W2bf   = (unsigned short*)(ws + 1015808);  // 786432 f
    unsigned short* W3bf   = (unsigned short*)(ws + 1802240);  // 196608 f
    float* Yobs  = ws + 1998848;                               // 393216 f
    float* Y0all = ws + 2392064;                               // 393216 f
    float* QOFF  = ws + 2785280;                               // 1024 f
    float* vq    = ws + 2786304;                               // 3072 f
    float* q     = ws + 2789376;                               // 76800 f

    prep_kernel<<<3916, 256, 0, stream>>>(obs, W1, W2, W3, Wp,
                                          obs_bf, W1Cbf, W2bf, W3bf, W1AT, vq);
    yobs_kernel<<<dim3(2,4,6), 256, 0, stream>>>(obs_bf, W1AT, b1, Yobs);
    chain_kernel<<<BATCH, 1024, 0, stream>>>(Yobs, W1, W1Cbf, W2bf, W3bf, b2, b3, actions, Wp, bp, Y0all, QOFF);
    sweep_kernel<<<768, 512, 0, stream>>>(Y0all, W1, W2, b2, vq, QOFF, q);
    lse_kernel<<<BATCH, 256, 0, stream>>>(q, out);
}